// Round 4
// baseline (271.331 us; speedup 1.0000x reference)
//
#include <hip/hip_runtime.h>

typedef __attribute__((ext_vector_type(8))) __bf16 bf16x8;
typedef __attribute__((ext_vector_type(4))) float f32x4;

#define DEVI static __device__ __forceinline__

DEVI unsigned short f2bf(float f) {
  unsigned int u = __float_as_uint(f);
  u += 0x7fffu + ((u >> 16) & 1u);
  return (unsigned short)(u >> 16);
}
DEVI float bf2f(unsigned short s) {
  return __uint_as_float(((unsigned int)s) << 16);
}

union Frag {
  bf16x8 v;
  __bf16 hf[8];
  unsigned short h[8];
  unsigned int w[4];
};

typedef __attribute__((address_space(1))) const void gv_t;
typedef __attribute__((address_space(3))) void sv_t;
#define GLOAD_LDS16(gp, lp) __builtin_amdgcn_global_load_lds((gv_t*)(gp), (sv_t*)(lp), 16, 0, 0)

// 0.125 * log2(e)
#define QSCALE 0.18033688011112042f

// ---------------------------------------------------------------------------
// Prep: fp32->bf16 conversion (x slice + 4 weights) AND iRPE bucket table.
// ---------------------------------------------------------------------------
__global__ __launch_bounds__(256) void k_prep(
    const float* __restrict__ x, const float* __restrict__ wq,
    const float* __restrict__ wk, const float* __restrict__ wv,
    const float* __restrict__ pw,
    unsigned short* __restrict__ xb, unsigned short* __restrict__ wb,
    unsigned char* __restrict__ bkt)
{
  int t = blockIdx.x * 256 + threadIdx.x;
  if (t >= 1572864) {  // bucket table
    int q = t - 1572864;               // 0..262143
    int i = q >> 9, j = q & 511;
    int ir = i / 23, ic = i - ir * 23;
    int jr = j / 23, jc = j - jr * 23;
    int dy = ir - jr, dx = ic - jc;
    double dis = rint(sqrt((double)(dy * dy + dx * dx)));
    int v;
    if (dis <= 1.9) {
      v = (int)rint(dis);
    } else {
      double far = rint(1.9 + log(dis / 1.9) * (1.9 / log(8.0)));
      v = (int)fmin(far, 3.8);
    }
    bkt[q] = (unsigned char)v;
    return;
  }
  const float* src;
  unsigned short* dst;
  if (t < 1048576) {
    long e0 = (long)t << 3;
    int m = (int)(e0 >> 10), cc = (int)(e0 & 1023);
    int b = m >> 9, i = m & 511;
    src = x + (((long)(b << 10) + i) << 10) + cc;
    dst = xb + ((long)m << 10) + cc;
  } else {
    long e0 = (long)(t - 1048576) << 3;
    int mat = (int)(e0 >> 20);
    long off = e0 & 1048575;
    const float* s = (mat == 0) ? wq : (mat == 1) ? wk : (mat == 2) ? wv : pw;
    src = s + off;
    dst = wb + e0;
  }
  float4 a = *(const float4*)src;
  float4 b4 = *(const float4*)(src + 4);
  uint4 o;
  o.x = f2bf(a.x)  | ((unsigned)f2bf(a.y)  << 16);
  o.y = f2bf(a.z)  | ((unsigned)f2bf(a.w)  << 16);
  o.z = f2bf(b4.x) | ((unsigned)f2bf(b4.y) << 16);
  o.w = f2bf(b4.z) | ((unsigned)f2bf(b4.w) << 16);
  *(uint4*)dst = o;
}

// ---------------------------------------------------------------------------
// bf16 NT GEMM, counted-vmcnt ring-3 pipeline + st_16x32 LDS swizzle.
// BM=256, BN=128, BK=32, 512 thr = 8 waves (4x2), per-wave 64x64.
// MODE 0: N=3072 -> Q (prescaled), K head-major, V transposed per head.
// MODE 1: N=1024 -> fp32 out + bias
// ---------------------------------------------------------------------------
template<int MODE>
__global__ __launch_bounds__(512) void k_gemm(
    const unsigned short* __restrict__ A,
    const unsigned short* __restrict__ Bw,
    unsigned short* __restrict__ qh, unsigned short* __restrict__ kh,
    unsigned short* __restrict__ vt,
    float* __restrict__ out, const float* __restrict__ bias)
{
  __shared__ unsigned short sL[3 * 12288];   // 73728 B

  const int NTN = (MODE == 0) ? 24 : 8;
  const int nwg = (MODE == 0) ? 768 : 256;
  const int cpx = nwg / 8;
  const int bid = blockIdx.x;
  const int swz = (bid & 7) * cpx + (bid >> 3);     // bijective XCD swizzle
  const int tileN = swz % NTN, tileM = swz / NTN;

  const int tid = threadIdx.x;
  const int w = tid >> 6, lane = tid & 63;
  const int g = lane >> 4, c = lane & 15;
  const int wm = w >> 1, wn = w & 1;

  const int sk = (g * 8) ^ ((c & 8) ? 16 : 0);
  int offA[4], offB[4];
#pragma unroll
  for (int i = 0; i < 4; ++i) {
    offA[i] = (wm * 4 + i) * 512 + c * 32 + sk;
    offB[i] = 8192 + (wn * 4 + i) * 512 + c * 32 + sk;
  }

  const int colb = ((lane & 3) * 8) ^ ((lane >= 32) ? 16 : 0);
  const unsigned short* gA0 = A  + ((long)(tileM * 256 + w * 32 + (lane >> 2))) * 1024 + colb;
  const unsigned short* gA1 = gA0 + 16 * 1024;
  const unsigned short* gB0 = Bw + ((long)(tileN * 128 + w * 16 + (lane >> 2))) * 1024 + colb;

#define STAGE(ktile, buf) do {                                             \
    const long ko_ = (long)(ktile) * 32;                                   \
    char* base_ = (char*)sL + (buf) * 24576;                               \
    GLOAD_LDS16(gA0 + ko_, base_ + (w * 2) * 1024 + lane * 16);            \
    GLOAD_LDS16(gA1 + ko_, base_ + (w * 2 + 1) * 1024 + lane * 16);        \
    GLOAD_LDS16(gB0 + ko_, base_ + 16384 + w * 1024 + lane * 16);          \
  } while (0)

  f32x4 acc[4][4] = {};

  STAGE(0, 0);
  STAGE(1, 1);

  int rb = 0, wbuf = 2;
  for (int t = 0; t < 32; ++t) {
    asm volatile("s_waitcnt vmcnt(3)" ::: "memory");
    __builtin_amdgcn_s_barrier();
    int kt = t + 2; if (kt > 31) kt = 31;   // clamped junk stage at tail
    STAGE(kt, wbuf);

    const unsigned short* lb = sL + rb * 12288;
    bf16x8 af[4], bf[4];
#pragma unroll
    for (int i = 0; i < 4; ++i) af[i] = *(const bf16x8*)(lb + offA[i]);
#pragma unroll
    for (int i = 0; i < 4; ++i) bf[i] = *(const bf16x8*)(lb + offB[i]);

    __builtin_amdgcn_s_setprio(1);
#pragma unroll
    for (int mi = 0; mi < 4; ++mi)
#pragma unroll
      for (int ni = 0; ni < 4; ++ni)
        acc[mi][ni] = __builtin_amdgcn_mfma_f32_16x16x32_bf16(af[mi], bf[ni], acc[mi][ni], 0, 0, 0);
    __builtin_amdgcn_s_setprio(0);
    asm volatile("s_waitcnt lgkmcnt(0)" ::: "memory");

    rb = (rb == 2) ? 0 : rb + 1;
    wbuf = (wbuf == 2) ? 0 : wbuf + 1;
  }
  asm volatile("s_waitcnt vmcnt(0)" ::: "memory");
#undef STAGE

  const int m0 = tileM * 256 + wm * 64;
  const int n0 = tileN * 128 + wn * 64;

  if (MODE == 0) {
#pragma unroll
    for (int mi = 0; mi < 4; ++mi) {
      int mrow = m0 + mi * 16 + g * 4;
      int b = mrow >> 9, i = mrow & 511;
#pragma unroll
      for (int ni = 0; ni < 4; ++ni) {
        int n = n0 + ni * 16 + c;
        int mat = n >> 10;
        int cc = n & 1023;
        int h = cc >> 6, d = cc & 63;
        long bh = (long)(b * 16 + h);
        if (mat == 2) {
          unsigned int w0 = f2bf(acc[mi][ni][0]) | ((unsigned)f2bf(acc[mi][ni][1]) << 16);
          unsigned int w1 = f2bf(acc[mi][ni][2]) | ((unsigned)f2bf(acc[mi][ni][3]) << 16);
          *(uint2*)(vt + (bh * 64 + d) * 512 + i) = make_uint2(w0, w1);
        } else {
          float sc = (mat == 0) ? QSCALE : 1.0f;   // prescale Q for exp2 softmax
          unsigned short* dst = (mat == 0 ? qh : kh) + (bh * 512 + i) * 64 + d;
#pragma unroll
          for (int r = 0; r < 4; ++r)
            dst[(long)r * 64] = f2bf(acc[mi][ni][r] * sc);
        }
      }
    }
  } else {
#pragma unroll
    for (int mi = 0; mi < 4; ++mi) {
      int mrow = m0 + mi * 16 + g * 4;
#pragma unroll
      for (int ni = 0; ni < 4; ++ni) {
        int n = n0 + ni * 16 + c;
        float bv = bias[n];
#pragma unroll
        for (int r = 0; r < 4; ++r)
          out[(long)(mrow + r) * 1024 + n] = acc[mi][ni][r] + bv;
      }
    }
  }
}

// ---------------------------------------------------------------------------
// Fused attention v4: 1024 blocks x 256 thr (4 waves), 4 blocks/head grouped
// per XCD (K/V L2 reuse), 32 q-rows/wave (it=2). exp2 no-max softmax
// (Q prescaled, lt x8). K/bkt reg ping-pong prefetch. j-loop NOT unrolled
// (2 compact bodies, ~3KB code) to stay inside L1I.
// ---------------------------------------------------------------------------
__global__ __launch_bounds__(256, 4) void k_attn(
    const unsigned short* __restrict__ qh, const unsigned short* __restrict__ kh,
    const unsigned short* __restrict__ vt, const float* __restrict__ rpe,
    const unsigned char* __restrict__ bkt, unsigned short* __restrict__ ao)
{
  __shared__ float lt_lds[128 * 9];
  const int bid = blockIdx.x;
  const int sbid = (bid & 7) * 128 + (bid >> 3);    // bijective: head's 4 blocks on one XCD
  const int head = sbid >> 2, seg = sbid & 3;
  const int b = head >> 4, h = head & 15;
  const int w = threadIdx.x >> 6, lane = threadIdx.x & 63;
  const int g = lane >> 4, c = lane & 15;
  const int qloc = w * 32;                 // local q-row base (0..96)
  const int qg = seg * 128 + qloc;         // q-row base within head (0..480)
  const unsigned short* Q = qh + (long)head * 512 * 64;
  const unsigned short* K = kh + (long)head * 512 * 64;
  const unsigned short* V = vt + (long)head * 64 * 512;

  // --- load Q fragments (persist; prescaled by QSCALE) ---
  Frag qu[2][2];
#pragma unroll
  for (int it = 0; it < 2; ++it)
#pragma unroll
    for (int kk = 0; kk < 2; ++kk)
      qu[it][kk].v = *(const bf16x8*)(Q + (qg + it * 16 + c) * 64 + kk * 32 + g * 8);

  // --- lt[i][n] = sum_d q'[i][d]*rpe[d][n]; stored x8 = log2e * lt_orig ---
  float lt[2][7] = {};
#pragma unroll
  for (int kk = 0; kk < 2; ++kk)
#pragma unroll
    for (int tt = 0; tt < 8; ++tt) {
      int d = kk * 32 + g * 8 + tt;
      const float* rr = rpe + d * 7;
      float r0 = rr[0], r1 = rr[1], r2 = rr[2], r3 = rr[3], r4 = rr[4], r5 = rr[5], r6 = rr[6];
#pragma unroll
      for (int it = 0; it < 2; ++it) {
        float qv = bf2f(qu[it][kk].h[tt]);
        lt[it][0] += qv * r0; lt[it][1] += qv * r1; lt[it][2] += qv * r2;
        lt[it][3] += qv * r3; lt[it][4] += qv * r4; lt[it][5] += qv * r5;
        lt[it][6] += qv * r6;
      }
    }
#pragma unroll
  for (int it = 0; it < 2; ++it)
#pragma unroll
    for (int n = 0; n < 7; ++n) {
      float v = lt[it][n];
      v += __shfl_xor(v, 16);
      v += __shfl_xor(v, 32);
      if (g == 0) lt_lds[(qloc + it * 16 + c) * 9 + n] = v * 8.0f;
    }
  // wave-local write->read: no barrier needed

  int rowb36[2];
  const unsigned char* bktp[2];
#pragma unroll
  for (int it = 0; it < 2; ++it) {
    int row = qloc + it * 16 + c;
    rowb36[it] = row * 36;
    bktp[it] = bkt + (long)(qg + it * 16 + c) * 512 + g * 8;
  }

  f32x4 oacc[4][2] = {};          // [dt][it]
  float lp[2] = {0.f, 0.f};
  const int jperm = (c >> 2) * 8 + (c & 3);

  Frag kfA[2][2], kfB[2][2];
  uint2 bbA[2], bbB[2];

#define LOADKB(KF, BB, jb_) do {                                           \
    const int jp0_ = (jb_) + jperm;                                        \
    _Pragma("unroll")                                                      \
    for (int jt_ = 0; jt_ < 2; ++jt_)                                      \
      _Pragma("unroll")                                                    \
      for (int kk_ = 0; kk_ < 2; ++kk_)                                    \
        KF[jt_][kk_].v = *(const bf16x8*)(K + (jp0_ + jt_ * 4) * 64 + kk_ * 32 + g * 8); \
    _Pragma("unroll")                                                      \
    for (int it_ = 0; it_ < 2; ++it_)                                      \
      BB[it_] = *(const uint2*)(bktp[it_] + (jb_));                        \
  } while (0)

#define BODY(KC, BBc, KN, BBn, jb_, jn_) do {                              \
    bf16x8 vf[4];                                                          \
    _Pragma("unroll")                                                      \
    for (int dt_ = 0; dt_ < 4; ++dt_)                                      \
      vf[dt_] = *(const bf16x8*)(V + (dt_ * 16 + c) * 512 + (jb_) + g * 8);\
    LOADKB(KN, BBn, jn_);                                                  \
    f32x4 s[2][2];                                                         \
    __builtin_amdgcn_s_setprio(1);                                         \
    _Pragma("unroll")                                                      \
    for (int jt_ = 0; jt_ < 2; ++jt_)                                      \
      _Pragma("unroll")                                                    \
      for (int it_ = 0; it_ < 2; ++it_) {                                  \
        f32x4 z = {0.f, 0.f, 0.f, 0.f};                                    \
        z = __builtin_amdgcn_mfma_f32_16x16x32_bf16(KC[jt_][0].v, qu[it_][0].v, z, 0, 0, 0); \
        s[jt_][it_] = __builtin_amdgcn_mfma_f32_16x16x32_bf16(KC[jt_][1].v, qu[it_][1].v, z, 0, 0, 0); \
      }                                                                    \
    __builtin_amdgcn_s_setprio(0);                                         \
    Frag pfr[2];                                                           \
    _Pragma("unroll")                                                      \
    for (int it_ = 0; it_ < 2; ++it_) {                                    \
      float ps_ = 0.f;                                                     \
      _Pragma("unroll")                                                    \
      for (int jt_ = 0; jt_ < 2; ++jt_) {                                  \
        unsigned int bw_ = jt_ ? BBc[it_].y : BBc[it_].x;                  \
        _Pragma("unroll")                                                  \
        for (int r_ = 0; r_ < 4; ++r_) {                                   \
          int bno_ = (bw_ >> (8 * r_)) & 255;                              \
          float bias_ = *(const float*)((const char*)lt_lds + rowb36[it_] + (bno_ << 2)); \
          float sv_ = s[jt_][it_][r_] + bias_;                             \
          float p_;                                                        \
          asm("v_exp_f32 %0, %1" : "=v"(p_) : "v"(sv_));                   \
          ps_ += p_;                                                       \
          pfr[it_].hf[jt_ * 4 + r_] = (__bf16)p_;                          \
        }                                                                  \
      }                                                                    \
      lp[it_] += ps_;                                                      \
    }                                                                      \
    __builtin_amdgcn_s_setprio(1);                                         \
    _Pragma("unroll")                                                      \
    for (int dt_ = 0; dt_ < 4; ++dt_)                                      \
      _Pragma("unroll")                                                    \
      for (int it_ = 0; it_ < 2; ++it_)                                    \
        oacc[dt_][it_] = __builtin_amdgcn_mfma_f32_16x16x32_bf16(vf[dt_], pfr[it_].v, oacc[dt_][it_], 0, 0, 0); \
    __builtin_amdgcn_s_setprio(0);                                         \
  } while (0)

  LOADKB(kfA, bbA, 0);
#pragma unroll 1
  for (int jb = 0; jb < 512; jb += 64) {
    int j2 = jb + 32;
    int j3 = (jb + 64 < 512) ? (jb + 64) : 480;   // clamped junk prefetch at tail
    BODY(kfA, bbA, kfB, bbB, jb, j2);
    BODY(kfB, bbB, kfA, bbA, j2, j3);
  }
#undef BODY
#undef LOADKB

  float li[2];
#pragma unroll
  for (int it = 0; it < 2; ++it) {
    float v = lp[it];
    v += __shfl_xor(v, 16);
    v += __shfl_xor(v, 32);
    li[it] = 1.0f / v;
  }
#pragma unroll
  for (int dt = 0; dt < 4; ++dt)
#pragma unroll
    for (int it = 0; it < 2; ++it) {
      int irow = qg + it * 16 + c;
      int d0 = dt * 16 + g * 4;
      unsigned int w0 = f2bf(oacc[dt][it][0] * li[it]) | ((unsigned)f2bf(oacc[dt][it][1] * li[it]) << 16);
      unsigned int w1 = f2bf(oacc[dt][it][2] * li[it]) | ((unsigned)f2bf(oacc[dt][it][3] * li[it]) << 16);
      *(uint2*)(ao + ((long)(b * 512 + irow)) * 1024 + h * 64 + d0) = make_uint2(w0, w1);
    }
}

// ---------------------------------------------------------------------------
extern "C" void kernel_launch(void* const* d_in, const int* in_sizes, int n_in,
                              void* d_out, int out_size, void* d_ws, size_t ws_size,
                              hipStream_t stream) {
  const float* x   = (const float*)d_in[0];
  const float* wq  = (const float*)d_in[1];
  const float* wk  = (const float*)d_in[2];
  const float* wv  = (const float*)d_in[3];
  const float* rpe = (const float*)d_in[4];
  const float* pw  = (const float*)d_in[5];
  const float* pb  = (const float*)d_in[6];
  float* out = (float*)d_out;

  char* ws = (char*)d_ws;
  unsigned short* xb  = (unsigned short*)(ws);                 // 8192x1024 bf16 (16 MB)
  unsigned short* wb  = (unsigned short*)(ws + 16777216);      // 4x1024x1024 bf16 (8 MB)
  unsigned short* qhp = (unsigned short*)(ws + 25165824);      // [bh][512][64]
  unsigned short* khp = (unsigned short*)(ws + 41943040);      // [bh][512][64]
  unsigned short* vtp = (unsigned short*)(ws + 58720256);      // [bh][64][512]
  unsigned char*  bkt = (unsigned char*)(ws + 75497472);       // 512x512
  unsigned short* aop = xb;                                    // alias: xb dead after QKV gemm

  k_prep<<<dim3(7168), dim3(256), 0, stream>>>(x, wq, wk, wv, pw, xb, wb, bkt);
  k_gemm<0><<<dim3(768), dim3(512), 0, stream>>>(xb, wb, qhp, khp, vtp, nullptr, nullptr);
  k_attn<<<dim3(1024), dim3(256), 0, stream>>>(qhp, khp, vtp, rpe, bkt, aop);
  k_gemm<1><<<dim3(256), dim3(512), 0, stream>>>(aop, wb + 3 * 1048576, nullptr, nullptr, nullptr, out, pb);
}

// Round 5
// 178.090 us; speedup vs baseline: 1.5236x; 1.5236x over previous
//
#include <hip/hip_runtime.h>

typedef __attribute__((ext_vector_type(8))) __bf16 bf16x8;
typedef __attribute__((ext_vector_type(4))) float f32x4;

#define DEVI static __device__ __forceinline__

DEVI unsigned short f2bf(float f) {
  unsigned int u = __float_as_uint(f);
  u += 0x7fffu + ((u >> 16) & 1u);
  return (unsigned short)(u >> 16);
}
DEVI float bf2f(unsigned short s) {
  return __uint_as_float(((unsigned int)s) << 16);
}

union Frag {
  bf16x8 v;
  __bf16 hf[8];
  unsigned short h[8];
  unsigned int w[4];
};

typedef __attribute__((address_space(1))) const void gv_t;
typedef __attribute__((address_space(3))) void sv_t;
#define GLOAD_LDS16(gp, lp) __builtin_amdgcn_global_load_lds((gv_t*)(gp), (sv_t*)(lp), 16, 0, 0)

// 0.125 * log2(e)
#define QSCALE 0.18033688011112042f

// ---------------------------------------------------------------------------
// Prep: fp32->bf16 conversion (x slice + 4 weights) AND iRPE bucket table.
// ---------------------------------------------------------------------------
__global__ __launch_bounds__(256) void k_prep(
    const float* __restrict__ x, const float* __restrict__ wq,
    const float* __restrict__ wk, const float* __restrict__ wv,
    const float* __restrict__ pw,
    unsigned short* __restrict__ xb, unsigned short* __restrict__ wb,
    unsigned char* __restrict__ bkt)
{
  int t = blockIdx.x * 256 + threadIdx.x;
  if (t >= 1572864) {  // bucket table
    int q = t - 1572864;               // 0..262143
    int i = q >> 9, j = q & 511;
    int ir = i / 23, ic = i - ir * 23;
    int jr = j / 23, jc = j - jr * 23;
    int dy = ir - jr, dx = ic - jc;
    double dis = rint(sqrt((double)(dy * dy + dx * dx)));
    int v;
    if (dis <= 1.9) {
      v = (int)rint(dis);
    } else {
      double far = rint(1.9 + log(dis / 1.9) * (1.9 / log(8.0)));
      v = (int)fmin(far, 3.8);
    }
    bkt[q] = (unsigned char)v;
    return;
  }
  const float* src;
  unsigned short* dst;
  if (t < 1048576) {
    long e0 = (long)t << 3;
    int m = (int)(e0 >> 10), cc = (int)(e0 & 1023);
    int b = m >> 9, i = m & 511;
    src = x + (((long)(b << 10) + i) << 10) + cc;
    dst = xb + ((long)m << 10) + cc;
  } else {
    long e0 = (long)(t - 1048576) << 3;
    int mat = (int)(e0 >> 20);
    long off = e0 & 1048575;
    const float* s = (mat == 0) ? wq : (mat == 1) ? wk : (mat == 2) ? wv : pw;
    src = s + off;
    dst = wb + e0;
  }
  float4 a = *(const float4*)src;
  float4 b4 = *(const float4*)(src + 4);
  uint4 o;
  o.x = f2bf(a.x)  | ((unsigned)f2bf(a.y)  << 16);
  o.y = f2bf(a.z)  | ((unsigned)f2bf(a.w)  << 16);
  o.z = f2bf(b4.x) | ((unsigned)f2bf(b4.y) << 16);
  o.w = f2bf(b4.z) | ((unsigned)f2bf(b4.w) << 16);
  *(uint4*)dst = o;
}

// ---------------------------------------------------------------------------
// bf16 NT GEMM, counted-vmcnt ring-3 pipeline + st_16x32 LDS swizzle.
// BM=256, BN=128, BK=32, 512 thr = 8 waves (4x2), per-wave 64x64.
// MODE 0: N=3072 -> Q (prescaled), K head-major, V transposed per head.
// MODE 1: N=1024 -> fp32 out + bias
// ---------------------------------------------------------------------------
template<int MODE>
__global__ __launch_bounds__(512) void k_gemm(
    const unsigned short* __restrict__ A,
    const unsigned short* __restrict__ Bw,
    unsigned short* __restrict__ qh, unsigned short* __restrict__ kh,
    unsigned short* __restrict__ vt,
    float* __restrict__ out, const float* __restrict__ bias)
{
  __shared__ unsigned short sL[3 * 12288];   // 73728 B

  const int NTN = (MODE == 0) ? 24 : 8;
  const int nwg = (MODE == 0) ? 768 : 256;
  const int cpx = nwg / 8;
  const int bid = blockIdx.x;
  const int swz = (bid & 7) * cpx + (bid >> 3);     // bijective XCD swizzle
  const int tileN = swz % NTN, tileM = swz / NTN;

  const int tid = threadIdx.x;
  const int w = tid >> 6, lane = tid & 63;
  const int g = lane >> 4, c = lane & 15;
  const int wm = w >> 1, wn = w & 1;

  const int sk = (g * 8) ^ ((c & 8) ? 16 : 0);
  int offA[4], offB[4];
#pragma unroll
  for (int i = 0; i < 4; ++i) {
    offA[i] = (wm * 4 + i) * 512 + c * 32 + sk;
    offB[i] = 8192 + (wn * 4 + i) * 512 + c * 32 + sk;
  }

  const int colb = ((lane & 3) * 8) ^ ((lane >= 32) ? 16 : 0);
  const unsigned short* gA0 = A  + ((long)(tileM * 256 + w * 32 + (lane >> 2))) * 1024 + colb;
  const unsigned short* gA1 = gA0 + 16 * 1024;
  const unsigned short* gB0 = Bw + ((long)(tileN * 128 + w * 16 + (lane >> 2))) * 1024 + colb;

#define STAGE(ktile, buf) do {                                             \
    const long ko_ = (long)(ktile) * 32;                                   \
    char* base_ = (char*)sL + (buf) * 24576;                               \
    GLOAD_LDS16(gA0 + ko_, base_ + (w * 2) * 1024 + lane * 16);            \
    GLOAD_LDS16(gA1 + ko_, base_ + (w * 2 + 1) * 1024 + lane * 16);        \
    GLOAD_LDS16(gB0 + ko_, base_ + 16384 + w * 1024 + lane * 16);          \
  } while (0)

  f32x4 acc[4][4] = {};

  STAGE(0, 0);
  STAGE(1, 1);

  int rb = 0, wbuf = 2;
  for (int t = 0; t < 32; ++t) {
    asm volatile("s_waitcnt vmcnt(3)" ::: "memory");
    __builtin_amdgcn_s_barrier();
    int kt = t + 2; if (kt > 31) kt = 31;   // clamped junk stage at tail
    STAGE(kt, wbuf);

    const unsigned short* lb = sL + rb * 12288;
    bf16x8 af[4], bf[4];
#pragma unroll
    for (int i = 0; i < 4; ++i) af[i] = *(const bf16x8*)(lb + offA[i]);
#pragma unroll
    for (int i = 0; i < 4; ++i) bf[i] = *(const bf16x8*)(lb + offB[i]);

    __builtin_amdgcn_s_setprio(1);
#pragma unroll
    for (int mi = 0; mi < 4; ++mi)
#pragma unroll
      for (int ni = 0; ni < 4; ++ni)
        acc[mi][ni] = __builtin_amdgcn_mfma_f32_16x16x32_bf16(af[mi], bf[ni], acc[mi][ni], 0, 0, 0);
    __builtin_amdgcn_s_setprio(0);
    asm volatile("s_waitcnt lgkmcnt(0)" ::: "memory");

    rb = (rb == 2) ? 0 : rb + 1;
    wbuf = (wbuf == 2) ? 0 : wbuf + 1;
  }
  asm volatile("s_waitcnt vmcnt(0)" ::: "memory");
#undef STAGE

  const int m0 = tileM * 256 + wm * 64;
  const int n0 = tileN * 128 + wn * 64;

  if (MODE == 0) {
#pragma unroll
    for (int mi = 0; mi < 4; ++mi) {
      int mrow = m0 + mi * 16 + g * 4;
      int b = mrow >> 9, i = mrow & 511;
#pragma unroll
      for (int ni = 0; ni < 4; ++ni) {
        int n = n0 + ni * 16 + c;
        int mat = n >> 10;
        int cc = n & 1023;
        int h = cc >> 6, d = cc & 63;
        long bh = (long)(b * 16 + h);
        if (mat == 2) {
          unsigned int w0 = f2bf(acc[mi][ni][0]) | ((unsigned)f2bf(acc[mi][ni][1]) << 16);
          unsigned int w1 = f2bf(acc[mi][ni][2]) | ((unsigned)f2bf(acc[mi][ni][3]) << 16);
          *(uint2*)(vt + (bh * 64 + d) * 512 + i) = make_uint2(w0, w1);
        } else {
          float sc = (mat == 0) ? QSCALE : 1.0f;   // prescale Q for exp2 softmax
          unsigned short* dst = (mat == 0 ? qh : kh) + (bh * 512 + i) * 64 + d;
#pragma unroll
          for (int r = 0; r < 4; ++r)
            dst[(long)r * 64] = f2bf(acc[mi][ni][r] * sc);
        }
      }
    }
  } else {
#pragma unroll
    for (int mi = 0; mi < 4; ++mi) {
      int mrow = m0 + mi * 16 + g * 4;
#pragma unroll
      for (int ni = 0; ni < 4; ++ni) {
        int n = n0 + ni * 16 + c;
        float bv = bias[n];
#pragma unroll
        for (int r = 0; r < 4; ++r)
          out[(long)(mrow + r) * 1024 + n] = acc[mi][ni][r] + bv;
      }
    }
  }
}

// ---------------------------------------------------------------------------
// Fused attention v5: 256 blocks (1 head) x 512 thr (8 waves x 64 q-rows,
// it=4). exp2 no-max softmax (Q prescaled, lt x8). K/bkt reg ping-pong
// prefetch one tile ahead. j-loop NOT unrolled (#pragma unroll 1): exactly
// two ~350-inst bodies (~6KB) -> fits L1I. Plain launch_bounds(512): no
// forced VGPR cap (R4's (256,4) caused a 403MB scratch-spill disaster).
// ---------------------------------------------------------------------------
__global__ __launch_bounds__(512) void k_attn(
    const unsigned short* __restrict__ qh, const unsigned short* __restrict__ kh,
    const unsigned short* __restrict__ vt, const float* __restrict__ rpe,
    const unsigned char* __restrict__ bkt, unsigned short* __restrict__ ao)
{
  __shared__ float lt_lds[512 * 9];
  const int head = blockIdx.x;
  const int b = head >> 4, h = head & 15;
  const int w = threadIdx.x >> 6, lane = threadIdx.x & 63;
  const int g = lane >> 4, c = lane & 15;
  const int qbase = w * 64;
  const unsigned short* Q = qh + (long)head * 512 * 64;
  const unsigned short* K = kh + (long)head * 512 * 64;
  const unsigned short* V = vt + (long)head * 64 * 512;

  // --- load Q fragments (persist; prescaled by QSCALE) ---
  Frag qu[4][2];
#pragma unroll
  for (int it = 0; it < 4; ++it)
#pragma unroll
    for (int kk = 0; kk < 2; ++kk)
      qu[it][kk].v = *(const bf16x8*)(Q + (qbase + it * 16 + c) * 64 + kk * 32 + g * 8);

  // --- lt[i][n] = sum_d q'[i][d]*rpe[d][n]; stored x8 = log2e * lt_orig ---
  float lt[4][7] = {};
#pragma unroll
  for (int kk = 0; kk < 2; ++kk)
#pragma unroll
    for (int tt = 0; tt < 8; ++tt) {
      int d = kk * 32 + g * 8 + tt;
      const float* rr = rpe + d * 7;
      float r0 = rr[0], r1 = rr[1], r2 = rr[2], r3 = rr[3], r4 = rr[4], r5 = rr[5], r6 = rr[6];
#pragma unroll
      for (int it = 0; it < 4; ++it) {
        float qv = bf2f(qu[it][kk].h[tt]);
        lt[it][0] += qv * r0; lt[it][1] += qv * r1; lt[it][2] += qv * r2;
        lt[it][3] += qv * r3; lt[it][4] += qv * r4; lt[it][5] += qv * r5;
        lt[it][6] += qv * r6;
      }
    }
#pragma unroll
  for (int it = 0; it < 4; ++it)
#pragma unroll
    for (int n = 0; n < 7; ++n) {
      float v = lt[it][n];
      v += __shfl_xor(v, 16);
      v += __shfl_xor(v, 32);
      if (g == 0) lt_lds[(qbase + it * 16 + c) * 9 + n] = v * 8.0f;
    }
  // wave-local write->read: no barrier needed

  int rowb36[4];
  const unsigned char* bktp[4];
#pragma unroll
  for (int it = 0; it < 4; ++it) {
    int row = qbase + it * 16 + c;
    rowb36[it] = row * 36;
    bktp[it] = bkt + (long)row * 512 + g * 8;
  }

  f32x4 oacc[4][4] = {};          // [dt][it]
  float lp[4] = {0.f, 0.f, 0.f, 0.f};
  const int jperm = (c >> 2) * 8 + (c & 3);

  Frag kfA[2][2], kfB[2][2];
  uint2 bbA[4], bbB[4];

#define LOADKB(KF, BB, jb_) do {                                           \
    const int jp0_ = (jb_) + jperm;                                        \
    _Pragma("unroll")                                                      \
    for (int jt_ = 0; jt_ < 2; ++jt_)                                      \
      _Pragma("unroll")                                                    \
      for (int kk_ = 0; kk_ < 2; ++kk_)                                    \
        KF[jt_][kk_].v = *(const bf16x8*)(K + (jp0_ + jt_ * 4) * 64 + kk_ * 32 + g * 8); \
    _Pragma("unroll")                                                      \
    for (int it_ = 0; it_ < 4; ++it_)                                      \
      BB[it_] = *(const uint2*)(bktp[it_] + (jb_));                        \
  } while (0)

#define BODY(KC, BBc, KN, BBn, jb_, jn_) do {                              \
    bf16x8 vf[4];                                                          \
    _Pragma("unroll")                                                      \
    for (int dt_ = 0; dt_ < 4; ++dt_)                                      \
      vf[dt_] = *(const bf16x8*)(V + (dt_ * 16 + c) * 512 + (jb_) + g * 8);\
    LOADKB(KN, BBn, jn_);                                                  \
    f32x4 s[2][4];                                                         \
    __builtin_amdgcn_s_setprio(1);                                         \
    _Pragma("unroll")                                                      \
    for (int jt_ = 0; jt_ < 2; ++jt_)                                      \
      _Pragma("unroll")                                                    \
      for (int it_ = 0; it_ < 4; ++it_) {                                  \
        f32x4 z = {0.f, 0.f, 0.f, 0.f};                                    \
        z = __builtin_amdgcn_mfma_f32_16x16x32_bf16(KC[jt_][0].v, qu[it_][0].v, z, 0, 0, 0); \
        s[jt_][it_] = __builtin_amdgcn_mfma_f32_16x16x32_bf16(KC[jt_][1].v, qu[it_][1].v, z, 0, 0, 0); \
      }                                                                    \
    __builtin_amdgcn_s_setprio(0);                                         \
    Frag pfr[4];                                                           \
    _Pragma("unroll")                                                      \
    for (int it_ = 0; it_ < 4; ++it_) {                                    \
      float ps_ = 0.f;                                                     \
      _Pragma("unroll")                                                    \
      for (int jt_ = 0; jt_ < 2; ++jt_) {                                  \
        unsigned int bw_ = jt_ ? BBc[it_].y : BBc[it_].x;                  \
        _Pragma("unroll")                                                  \
        for (int r_ = 0; r_ < 4; ++r_) {                                   \
          int bno_ = (bw_ >> (8 * r_)) & 255;                              \
          float bias_ = *(const float*)((const char*)lt_lds + rowb36[it_] + (bno_ << 2)); \
          float sv_ = s[jt_][it_][r_] + bias_;                             \
          float p_;                                                        \
          asm("v_exp_f32 %0, %1" : "=v"(p_) : "v"(sv_));                   \
          ps_ += p_;                                                       \
          pfr[it_].hf[jt_ * 4 + r_] = (__bf16)p_;                          \
        }                                                                  \
      }                                                                    \
      lp[it_] += ps_;                                                      \
    }                                                                      \
    __builtin_amdgcn_s_setprio(1);                                         \
    _Pragma("unroll")                                                      \
    for (int dt_ = 0; dt_ < 4; ++dt_)                                      \
      _Pragma("unroll")                                                    \
      for (int it_ = 0; it_ < 4; ++it_)                                    \
        oacc[dt_][it_] = __builtin_amdgcn_mfma_f32_16x16x32_bf16(vf[dt_], pfr[it_].v, oacc[dt_][it_], 0, 0, 0); \
    __builtin_amdgcn_s_setprio(0);                                         \
  } while (0)

  LOADKB(kfA, bbA, 0);
#pragma unroll 1
  for (int jb = 0; jb < 512; jb += 64) {
    int j2 = jb + 32;
    int j3 = (jb + 64 < 512) ? (jb + 64) : 480;   // clamped junk prefetch at tail
    BODY(kfA, bbA, kfB, bbB, jb, j2);
    BODY(kfB, bbB, kfA, bbA, j2, j3);
  }
#undef BODY
#undef LOADKB

  float li[4];
#pragma unroll
  for (int it = 0; it < 4; ++it) {
    float v = lp[it];
    v += __shfl_xor(v, 16);
    v += __shfl_xor(v, 32);
    li[it] = 1.0f / v;
  }
#pragma unroll
  for (int dt = 0; dt < 4; ++dt)
#pragma unroll
    for (int it = 0; it < 4; ++it) {
      int irow = qbase + it * 16 + c;
      int d0 = dt * 16 + g * 4;
      unsigned int w0 = f2bf(oacc[dt][it][0] * li[it]) | ((unsigned)f2bf(oacc[dt][it][1] * li[it]) << 16);
      unsigned int w1 = f2bf(oacc[dt][it][2] * li[it]) | ((unsigned)f2bf(oacc[dt][it][3] * li[it]) << 16);
      *(uint2*)(ao + ((long)(b * 512 + irow)) * 1024 + h * 64 + d0) = make_uint2(w0, w1);
    }
}

// ---------------------------------------------------------------------------
extern "C" void kernel_launch(void* const* d_in, const int* in_sizes, int n_in,
                              void* d_out, int out_size, void* d_ws, size_t ws_size,
                              hipStream_t stream) {
  const float* x   = (const float*)d_in[0];
  const float* wq  = (const float*)d_in[1];
  const float* wk  = (const float*)d_in[2];
  const float* wv  = (const float*)d_in[3];
  const float* rpe = (const float*)d_in[4];
  const float* pw  = (const float*)d_in[5];
  const float* pb  = (const float*)d_in[6];
  float* out = (float*)d_out;

  char* ws = (char*)d_ws;
  unsigned short* xb  = (unsigned short*)(ws);                 // 8192x1024 bf16 (16 MB)
  unsigned short* wb  = (unsigned short*)(ws + 16777216);      // 4x1024x1024 bf16 (8 MB)
  unsigned short* qhp = (unsigned short*)(ws + 25165824);      // [bh][512][64]
  unsigned short* khp = (unsigned short*)(ws + 41943040);      // [bh][512][64]
  unsigned short* vtp = (unsigned short*)(ws + 58720256);      // [bh][64][512]
  unsigned char*  bkt = (unsigned char*)(ws + 75497472);       // 512x512
  unsigned short* aop = xb;                                    // alias: xb dead after QKV gemm

  k_prep<<<dim3(7168), dim3(256), 0, stream>>>(x, wq, wk, wv, pw, xb, wb, bkt);
  k_gemm<0><<<dim3(768), dim3(512), 0, stream>>>(xb, wb, qhp, khp, vtp, nullptr, nullptr);
  k_attn<<<dim3(256), dim3(512), 0, stream>>>(qhp, khp, vtp, rpe, bkt, aop);
  k_gemm<1><<<dim3(256), dim3(512), 0, stream>>>(aop, wb + 3 * 1048576, nullptr, nullptr, nullptr, out, pb);
}

// Round 6
// 177.788 us; speedup vs baseline: 1.5261x; 1.0017x over previous
//
#include <hip/hip_runtime.h>

typedef __attribute__((ext_vector_type(8))) __bf16 bf16x8;
typedef __attribute__((ext_vector_type(4))) float f32x4;

#define DEVI static __device__ __forceinline__

DEVI unsigned short f2bf(float f) {
  unsigned int u = __float_as_uint(f);
  u += 0x7fffu + ((u >> 16) & 1u);
  return (unsigned short)(u >> 16);
}
DEVI float bf2f(unsigned short s) {
  return __uint_as_float(((unsigned int)s) << 16);
}

union Frag {
  bf16x8 v;
  __bf16 hf[8];
  unsigned short h[8];
  unsigned int w[4];
};

typedef __attribute__((address_space(1))) const void gv_t;
typedef __attribute__((address_space(3))) void sv_t;
#define GLOAD_LDS16(gp, lp) __builtin_amdgcn_global_load_lds((gv_t*)(gp), (sv_t*)(lp), 16, 0, 0)

// 0.125 * log2(e)
#define QSCALE 0.18033688011112042f

// ---------------------------------------------------------------------------
// Prep: fp32->bf16 conversion (x slice + 4 weights) AND iRPE bucket table.
// ---------------------------------------------------------------------------
__global__ __launch_bounds__(256) void k_prep(
    const float* __restrict__ x, const float* __restrict__ wq,
    const float* __restrict__ wk, const float* __restrict__ wv,
    const float* __restrict__ pw,
    unsigned short* __restrict__ xb, unsigned short* __restrict__ wb,
    unsigned char* __restrict__ bkt)
{
  int t = blockIdx.x * 256 + threadIdx.x;
  if (t >= 1572864) {  // bucket table
    int q = t - 1572864;               // 0..262143
    int i = q >> 9, j = q & 511;
    int ir = i / 23, ic = i - ir * 23;
    int jr = j / 23, jc = j - jr * 23;
    int dy = ir - jr, dx = ic - jc;
    double dis = rint(sqrt((double)(dy * dy + dx * dx)));
    int v;
    if (dis <= 1.9) {
      v = (int)rint(dis);
    } else {
      double far = rint(1.9 + log(dis / 1.9) * (1.9 / log(8.0)));
      v = (int)fmin(far, 3.8);
    }
    bkt[q] = (unsigned char)v;
    return;
  }
  const float* src;
  unsigned short* dst;
  if (t < 1048576) {
    long e0 = (long)t << 3;
    int m = (int)(e0 >> 10), cc = (int)(e0 & 1023);
    int b = m >> 9, i = m & 511;
    src = x + (((long)(b << 10) + i) << 10) + cc;
    dst = xb + ((long)m << 10) + cc;
  } else {
    long e0 = (long)(t - 1048576) << 3;
    int mat = (int)(e0 >> 20);
    long off = e0 & 1048575;
    const float* s = (mat == 0) ? wq : (mat == 1) ? wk : (mat == 2) ? wv : pw;
    src = s + off;
    dst = wb + e0;
  }
  float4 a = *(const float4*)src;
  float4 b4 = *(const float4*)(src + 4);
  uint4 o;
  o.x = f2bf(a.x)  | ((unsigned)f2bf(a.y)  << 16);
  o.y = f2bf(a.z)  | ((unsigned)f2bf(a.w)  << 16);
  o.z = f2bf(b4.x) | ((unsigned)f2bf(b4.y) << 16);
  o.w = f2bf(b4.z) | ((unsigned)f2bf(b4.w) << 16);
  *(uint4*)dst = o;
}

// ---------------------------------------------------------------------------
// bf16 NT GEMM, counted-vmcnt ring-3 pipeline + st_16x32 LDS swizzle.
// BM=256, BN=128, BK=32, 512 thr = 8 waves (4x2), per-wave 64x64.
// MODE 0: N=3072 -> Q (prescaled), K head-major, V transposed per head.
// MODE 1: N=1024 -> fp32 out + bias
// ---------------------------------------------------------------------------
template<int MODE>
__global__ __launch_bounds__(512) void k_gemm(
    const unsigned short* __restrict__ A,
    const unsigned short* __restrict__ Bw,
    unsigned short* __restrict__ qh, unsigned short* __restrict__ kh,
    unsigned short* __restrict__ vt,
    float* __restrict__ out, const float* __restrict__ bias)
{
  __shared__ unsigned short sL[3 * 12288];   // 73728 B

  const int NTN = (MODE == 0) ? 24 : 8;
  const int nwg = (MODE == 0) ? 768 : 256;
  const int cpx = nwg / 8;
  const int bid = blockIdx.x;
  const int swz = (bid & 7) * cpx + (bid >> 3);     // bijective XCD swizzle
  const int tileN = swz % NTN, tileM = swz / NTN;

  const int tid = threadIdx.x;
  const int w = tid >> 6, lane = tid & 63;
  const int g = lane >> 4, c = lane & 15;
  const int wm = w >> 1, wn = w & 1;

  const int sk = (g * 8) ^ ((c & 8) ? 16 : 0);
  int offA[4], offB[4];
#pragma unroll
  for (int i = 0; i < 4; ++i) {
    offA[i] = (wm * 4 + i) * 512 + c * 32 + sk;
    offB[i] = 8192 + (wn * 4 + i) * 512 + c * 32 + sk;
  }

  const int colb = ((lane & 3) * 8) ^ ((lane >= 32) ? 16 : 0);
  const unsigned short* gA0 = A  + ((long)(tileM * 256 + w * 32 + (lane >> 2))) * 1024 + colb;
  const unsigned short* gA1 = gA0 + 16 * 1024;
  const unsigned short* gB0 = Bw + ((long)(tileN * 128 + w * 16 + (lane >> 2))) * 1024 + colb;

#define STAGE(ktile, buf) do {                                             \
    const long ko_ = (long)(ktile) * 32;                                   \
    char* base_ = (char*)sL + (buf) * 24576;                               \
    GLOAD_LDS16(gA0 + ko_, base_ + (w * 2) * 1024 + lane * 16);            \
    GLOAD_LDS16(gA1 + ko_, base_ + (w * 2 + 1) * 1024 + lane * 16);        \
    GLOAD_LDS16(gB0 + ko_, base_ + 16384 + w * 1024 + lane * 16);          \
  } while (0)

  f32x4 acc[4][4] = {};

  STAGE(0, 0);
  STAGE(1, 1);

  int rb = 0, wbuf = 2;
  for (int t = 0; t < 32; ++t) {
    asm volatile("s_waitcnt vmcnt(3)" ::: "memory");
    __builtin_amdgcn_s_barrier();
    int kt = t + 2; if (kt > 31) kt = 31;   // clamped junk stage at tail
    STAGE(kt, wbuf);

    const unsigned short* lb = sL + rb * 12288;
    bf16x8 af[4], bf[4];
#pragma unroll
    for (int i = 0; i < 4; ++i) af[i] = *(const bf16x8*)(lb + offA[i]);
#pragma unroll
    for (int i = 0; i < 4; ++i) bf[i] = *(const bf16x8*)(lb + offB[i]);

    __builtin_amdgcn_s_setprio(1);
#pragma unroll
    for (int mi = 0; mi < 4; ++mi)
#pragma unroll
      for (int ni = 0; ni < 4; ++ni)
        acc[mi][ni] = __builtin_amdgcn_mfma_f32_16x16x32_bf16(af[mi], bf[ni], acc[mi][ni], 0, 0, 0);
    __builtin_amdgcn_s_setprio(0);
    asm volatile("s_waitcnt lgkmcnt(0)" ::: "memory");

    rb = (rb == 2) ? 0 : rb + 1;
    wbuf = (wbuf == 2) ? 0 : wbuf + 1;
  }
  asm volatile("s_waitcnt vmcnt(0)" ::: "memory");
#undef STAGE

  const int m0 = tileM * 256 + wm * 64;
  const int n0 = tileN * 128 + wn * 64;

  if (MODE == 0) {
#pragma unroll
    for (int mi = 0; mi < 4; ++mi) {
      int mrow = m0 + mi * 16 + g * 4;
      int b = mrow >> 9, i = mrow & 511;
#pragma unroll
      for (int ni = 0; ni < 4; ++ni) {
        int n = n0 + ni * 16 + c;
        int mat = n >> 10;
        int cc = n & 1023;
        int h = cc >> 6, d = cc & 63;
        long bh = (long)(b * 16 + h);
        if (mat == 2) {
          unsigned int w0 = f2bf(acc[mi][ni][0]) | ((unsigned)f2bf(acc[mi][ni][1]) << 16);
          unsigned int w1 = f2bf(acc[mi][ni][2]) | ((unsigned)f2bf(acc[mi][ni][3]) << 16);
          *(uint2*)(vt + (bh * 64 + d) * 512 + i) = make_uint2(w0, w1);
        } else {
          float sc = (mat == 0) ? QSCALE : 1.0f;   // prescale Q for exp2 softmax
          unsigned short* dst = (mat == 0 ? qh : kh) + (bh * 512 + i) * 64 + d;
#pragma unroll
          for (int r = 0; r < 4; ++r)
            dst[(long)r * 64] = f2bf(acc[mi][ni][r] * sc);
        }
      }
    }
  } else {
#pragma unroll
    for (int mi = 0; mi < 4; ++mi) {
      int mrow = m0 + mi * 16 + g * 4;
#pragma unroll
      for (int ni = 0; ni < 4; ++ni) {
        int n = n0 + ni * 16 + c;
        float bv = bias[n];
#pragma unroll
        for (int r = 0; r < 4; ++r)
          out[(long)(mrow + r) * 1024 + n] = acc[mi][ni][r] + bv;
      }
    }
  }
}

// ---------------------------------------------------------------------------
// Fused attention v6: 1024 blocks x 256 thr (4 waves x 32 q-rows, it=2),
// 4 blocks/head grouped per XCD (K/V L2 reuse). exp2 no-max softmax
// (Q prescaled, lt x8). K/bkt reg ping-pong prefetch. #pragma unroll 1
// j-loop (2 compact bodies ~2.5KB, L1I-safe). PLAIN launch_bounds(256):
// natural VGPR (~96-110) -> 4-5 waves/SIMD, no spill (R4's (256,4) forced
// VGPR=64 and caused 403MB scratch traffic).
// ---------------------------------------------------------------------------
__global__ __launch_bounds__(256) void k_attn(
    const unsigned short* __restrict__ qh, const unsigned short* __restrict__ kh,
    const unsigned short* __restrict__ vt, const float* __restrict__ rpe,
    const unsigned char* __restrict__ bkt, unsigned short* __restrict__ ao)
{
  __shared__ float lt_lds[128 * 9];
  const int bid = blockIdx.x;
  const int sbid = (bid & 7) * 128 + (bid >> 3);    // bijective: head's 4 blocks on one XCD
  const int head = sbid >> 2, seg = sbid & 3;
  const int b = head >> 4, h = head & 15;
  const int w = threadIdx.x >> 6, lane = threadIdx.x & 63;
  const int g = lane >> 4, c = lane & 15;
  const int qloc = w * 32;                 // local q-row base (0..96)
  const int qg = seg * 128 + qloc;         // q-row base within head (0..480)
  const unsigned short* Q = qh + (long)head * 512 * 64;
  const unsigned short* K = kh + (long)head * 512 * 64;
  const unsigned short* V = vt + (long)head * 64 * 512;

  // --- load Q fragments (persist; prescaled by QSCALE) ---
  Frag qu[2][2];
#pragma unroll
  for (int it = 0; it < 2; ++it)
#pragma unroll
    for (int kk = 0; kk < 2; ++kk)
      qu[it][kk].v = *(const bf16x8*)(Q + (qg + it * 16 + c) * 64 + kk * 32 + g * 8);

  // --- lt[i][n] = sum_d q'[i][d]*rpe[d][n]; stored x8 = log2e * lt_orig ---
  float lt[2][7] = {};
#pragma unroll
  for (int kk = 0; kk < 2; ++kk)
#pragma unroll
    for (int tt = 0; tt < 8; ++tt) {
      int d = kk * 32 + g * 8 + tt;
      const float* rr = rpe + d * 7;
      float r0 = rr[0], r1 = rr[1], r2 = rr[2], r3 = rr[3], r4 = rr[4], r5 = rr[5], r6 = rr[6];
#pragma unroll
      for (int it = 0; it < 2; ++it) {
        float qv = bf2f(qu[it][kk].h[tt]);
        lt[it][0] += qv * r0; lt[it][1] += qv * r1; lt[it][2] += qv * r2;
        lt[it][3] += qv * r3; lt[it][4] += qv * r4; lt[it][5] += qv * r5;
        lt[it][6] += qv * r6;
      }
    }
#pragma unroll
  for (int it = 0; it < 2; ++it)
#pragma unroll
    for (int n = 0; n < 7; ++n) {
      float v = lt[it][n];
      v += __shfl_xor(v, 16);
      v += __shfl_xor(v, 32);
      if (g == 0) lt_lds[(qloc + it * 16 + c) * 9 + n] = v * 8.0f;
    }
  // wave-local write->read: no barrier needed

  int rowb36[2];
  const unsigned char* bktp[2];
#pragma unroll
  for (int it = 0; it < 2; ++it) {
    int row = qloc + it * 16 + c;
    rowb36[it] = row * 36;
    bktp[it] = bkt + (long)(qg + it * 16 + c) * 512 + g * 8;
  }

  f32x4 oacc[4][2] = {};          // [dt][it]
  float lp[2] = {0.f, 0.f};
  const int jperm = (c >> 2) * 8 + (c & 3);

  Frag kfA[2][2], kfB[2][2];
  uint2 bbA[2], bbB[2];

#define LOADKB(KF, BB, jb_) do {                                           \
    const int jp0_ = (jb_) + jperm;                                        \
    _Pragma("unroll")                                                      \
    for (int jt_ = 0; jt_ < 2; ++jt_)                                      \
      _Pragma("unroll")                                                    \
      for (int kk_ = 0; kk_ < 2; ++kk_)                                    \
        KF[jt_][kk_].v = *(const bf16x8*)(K + (jp0_ + jt_ * 4) * 64 + kk_ * 32 + g * 8); \
    _Pragma("unroll")                                                      \
    for (int it_ = 0; it_ < 2; ++it_)                                      \
      BB[it_] = *(const uint2*)(bktp[it_] + (jb_));                        \
  } while (0)

#define BODY(KC, BBc, KN, BBn, jb_, jn_) do {                              \
    bf16x8 vf[4];                                                          \
    _Pragma("unroll")                                                      \
    for (int dt_ = 0; dt_ < 4; ++dt_)                                      \
      vf[dt_] = *(const bf16x8*)(V + (dt_ * 16 + c) * 512 + (jb_) + g * 8);\
    LOADKB(KN, BBn, jn_);                                                  \
    f32x4 s[2][2];                                                         \
    __builtin_amdgcn_s_setprio(1);                                         \
    _Pragma("unroll")                                                      \
    for (int jt_ = 0; jt_ < 2; ++jt_)                                      \
      _Pragma("unroll")                                                    \
      for (int it_ = 0; it_ < 2; ++it_) {                                  \
        f32x4 z = {0.f, 0.f, 0.f, 0.f};                                    \
        z = __builtin_amdgcn_mfma_f32_16x16x32_bf16(KC[jt_][0].v, qu[it_][0].v, z, 0, 0, 0); \
        s[jt_][it_] = __builtin_amdgcn_mfma_f32_16x16x32_bf16(KC[jt_][1].v, qu[it_][1].v, z, 0, 0, 0); \
      }                                                                    \
    __builtin_amdgcn_s_setprio(0);                                         \
    Frag pfr[2];                                                           \
    _Pragma("unroll")                                                      \
    for (int it_ = 0; it_ < 2; ++it_) {                                    \
      float ps_ = 0.f;                                                     \
      _Pragma("unroll")                                                    \
      for (int jt_ = 0; jt_ < 2; ++jt_) {                                  \
        unsigned int bw_ = jt_ ? BBc[it_].y : BBc[it_].x;                  \
        _Pragma("unroll")                                                  \
        for (int r_ = 0; r_ < 4; ++r_) {                                   \
          int bno_ = (bw_ >> (8 * r_)) & 255;                              \
          float bias_ = *(const float*)((const char*)lt_lds + rowb36[it_] + (bno_ << 2)); \
          float sv_ = s[jt_][it_][r_] + bias_;                             \
          float p_;                                                        \
          asm("v_exp_f32 %0, %1" : "=v"(p_) : "v"(sv_));                   \
          ps_ += p_;                                                       \
          pfr[it_].hf[jt_ * 4 + r_] = (__bf16)p_;                          \
        }                                                                  \
      }                                                                    \
      lp[it_] += ps_;                                                      \
    }                                                                      \
    __builtin_amdgcn_s_setprio(1);                                         \
    _Pragma("unroll")                                                      \
    for (int dt_ = 0; dt_ < 4; ++dt_)                                      \
      _Pragma("unroll")                                                    \
      for (int it_ = 0; it_ < 2; ++it_)                                    \
        oacc[dt_][it_] = __builtin_amdgcn_mfma_f32_16x16x32_bf16(vf[dt_], pfr[it_].v, oacc[dt_][it_], 0, 0, 0); \
    __builtin_amdgcn_s_setprio(0);                                         \
  } while (0)

  LOADKB(kfA, bbA, 0);
#pragma unroll 1
  for (int jb = 0; jb < 512; jb += 64) {
    int j2 = jb + 32;
    int j3 = (jb + 64 < 512) ? (jb + 64) : 480;   // clamped junk prefetch at tail
    BODY(kfA, bbA, kfB, bbB, jb, j2);
    BODY(kfB, bbB, kfA, bbA, j2, j3);
  }
#undef BODY
#undef LOADKB

  float li[2];
#pragma unroll
  for (int it = 0; it < 2; ++it) {
    float v = lp[it];
    v += __shfl_xor(v, 16);
    v += __shfl_xor(v, 32);
    li[it] = 1.0f / v;
  }
#pragma unroll
  for (int dt = 0; dt < 4; ++dt)
#pragma unroll
    for (int it = 0; it < 2; ++it) {
      int irow = qg + it * 16 + c;
      int d0 = dt * 16 + g * 4;
      unsigned int w0 = f2bf(oacc[dt][it][0] * li[it]) | ((unsigned)f2bf(oacc[dt][it][1] * li[it]) << 16);
      unsigned int w1 = f2bf(oacc[dt][it][2] * li[it]) | ((unsigned)f2bf(oacc[dt][it][3] * li[it]) << 16);
      *(uint2*)(ao + ((long)(b * 512 + irow)) * 1024 + h * 64 + d0) = make_uint2(w0, w1);
    }
}

// ---------------------------------------------------------------------------
extern "C" void kernel_launch(void* const* d_in, const int* in_sizes, int n_in,
                              void* d_out, int out_size, void* d_ws, size_t ws_size,
                              hipStream_t stream) {
  const float* x   = (const float*)d_in[0];
  const float* wq  = (const float*)d_in[1];
  const float* wk  = (const float*)d_in[2];
  const float* wv  = (const float*)d_in[3];
  const float* rpe = (const float*)d_in[4];
  const float* pw  = (const float*)d_in[5];
  const float* pb  = (const float*)d_in[6];
  float* out = (float*)d_out;

  char* ws = (char*)d_ws;
  unsigned short* xb  = (unsigned short*)(ws);                 // 8192x1024 bf16 (16 MB)
  unsigned short* wb  = (unsigned short*)(ws + 16777216);      // 4x1024x1024 bf16 (8 MB)
  unsigned short* qhp = (unsigned short*)(ws + 25165824);      // [bh][512][64]
  unsigned short* khp = (unsigned short*)(ws + 41943040);      // [bh][512][64]
  unsigned short* vtp = (unsigned short*)(ws + 58720256);      // [bh][64][512]
  unsigned char*  bkt = (unsigned char*)(ws + 75497472);       // 512x512
  unsigned short* aop = xb;                                    // alias: xb dead after QKV gemm

  k_prep<<<dim3(7168), dim3(256), 0, stream>>>(x, wq, wk, wv, pw, xb, wb, bkt);
  k_gemm<0><<<dim3(768), dim3(512), 0, stream>>>(xb, wb, qhp, khp, vtp, nullptr, nullptr);
  k_attn<<<dim3(1024), dim3(256), 0, stream>>>(qhp, khp, vtp, rpe, bkt, aop);
  k_gemm<1><<<dim3(256), dim3(512), 0, stream>>>(aop, wb + 3 * 1048576, nullptr, nullptr, nullptr, out, pb);
}

// Round 7
// 151.554 us; speedup vs baseline: 1.7903x; 1.1731x over previous
//
#include <hip/hip_runtime.h>

typedef __attribute__((ext_vector_type(8))) __bf16 bf16x8;
typedef __attribute__((ext_vector_type(4))) float f32x4;

#define DEVI static __device__ __forceinline__

DEVI unsigned short f2bf(float f) {
  unsigned int u = __float_as_uint(f);
  u += 0x7fffu + ((u >> 16) & 1u);
  return (unsigned short)(u >> 16);
}
DEVI float bf2f(unsigned short s) {
  return __uint_as_float(((unsigned int)s) << 16);
}

union Frag {
  bf16x8 v;
  __bf16 hf[8];
  unsigned short h[8];
  unsigned int w[4];
};

typedef __attribute__((address_space(1))) const void gv_t;
typedef __attribute__((address_space(3))) void sv_t;
#define GLOAD_LDS16(gp, lp) __builtin_amdgcn_global_load_lds((gv_t*)(gp), (sv_t*)(lp), 16, 0, 0)

// 0.125 * log2(e)
#define QSCALE 0.18033688011112042f

// ---------------------------------------------------------------------------
// Prep: fp32->bf16 conversion (x slice + 4 weights) AND iRPE bucket table.
// ---------------------------------------------------------------------------
__global__ __launch_bounds__(256) void k_prep(
    const float* __restrict__ x, const float* __restrict__ wq,
    const float* __restrict__ wk, const float* __restrict__ wv,
    const float* __restrict__ pw,
    unsigned short* __restrict__ xb, unsigned short* __restrict__ wb,
    unsigned char* __restrict__ bkt)
{
  int t = blockIdx.x * 256 + threadIdx.x;
  if (t >= 1572864) {  // bucket table
    int q = t - 1572864;               // 0..262143
    int i = q >> 9, j = q & 511;
    int ir = i / 23, ic = i - ir * 23;
    int jr = j / 23, jc = j - jr * 23;
    int dy = ir - jr, dx = ic - jc;
    double dis = rint(sqrt((double)(dy * dy + dx * dx)));
    int v;
    if (dis <= 1.9) {
      v = (int)rint(dis);
    } else {
      double far = rint(1.9 + log(dis / 1.9) * (1.9 / log(8.0)));
      v = (int)fmin(far, 3.8);
    }
    bkt[q] = (unsigned char)v;
    return;
  }
  const float* src;
  unsigned short* dst;
  if (t < 1048576) {
    long e0 = (long)t << 3;
    int m = (int)(e0 >> 10), cc = (int)(e0 & 1023);
    int b = m >> 9, i = m & 511;
    src = x + (((long)(b << 10) + i) << 10) + cc;
    dst = xb + ((long)m << 10) + cc;
  } else {
    long e0 = (long)(t - 1048576) << 3;
    int mat = (int)(e0 >> 20);
    long off = e0 & 1048575;
    const float* s = (mat == 0) ? wq : (mat == 1) ? wk : (mat == 2) ? wv : pw;
    src = s + off;
    dst = wb + e0;
  }
  float4 a = *(const float4*)src;
  float4 b4 = *(const float4*)(src + 4);
  uint4 o;
  o.x = f2bf(a.x)  | ((unsigned)f2bf(a.y)  << 16);
  o.y = f2bf(a.z)  | ((unsigned)f2bf(a.w)  << 16);
  o.z = f2bf(b4.x) | ((unsigned)f2bf(b4.y) << 16);
  o.w = f2bf(b4.z) | ((unsigned)f2bf(b4.w) << 16);
  *(uint4*)dst = o;
}

// ---------------------------------------------------------------------------
// bf16 NT GEMM, counted-vmcnt ring-3 pipeline + st_16x32 LDS swizzle.
// BM=256, BN=128, BK=32, 512 thr = 8 waves (4x2), per-wave 64x64.
// MODE 0: N=3072 -> Q (prescaled), K head-major, V transposed per head.
// MODE 1: N=1024 -> fp32 out + bias
// ---------------------------------------------------------------------------
template<int MODE>
__global__ __launch_bounds__(512) void k_gemm(
    const unsigned short* __restrict__ A,
    const unsigned short* __restrict__ Bw,
    unsigned short* __restrict__ qh, unsigned short* __restrict__ kh,
    unsigned short* __restrict__ vt,
    float* __restrict__ out, const float* __restrict__ bias)
{
  __shared__ unsigned short sL[3 * 12288];   // 73728 B

  const int NTN = (MODE == 0) ? 24 : 8;
  const int nwg = (MODE == 0) ? 768 : 256;
  const int cpx = nwg / 8;
  const int bid = blockIdx.x;
  const int swz = (bid & 7) * cpx + (bid >> 3);     // bijective XCD swizzle
  const int tileN = swz % NTN, tileM = swz / NTN;

  const int tid = threadIdx.x;
  const int w = tid >> 6, lane = tid & 63;
  const int g = lane >> 4, c = lane & 15;
  const int wm = w >> 1, wn = w & 1;

  const int sk = (g * 8) ^ ((c & 8) ? 16 : 0);
  int offA[4], offB[4];
#pragma unroll
  for (int i = 0; i < 4; ++i) {
    offA[i] = (wm * 4 + i) * 512 + c * 32 + sk;
    offB[i] = 8192 + (wn * 4 + i) * 512 + c * 32 + sk;
  }

  const int colb = ((lane & 3) * 8) ^ ((lane >= 32) ? 16 : 0);
  const unsigned short* gA0 = A  + ((long)(tileM * 256 + w * 32 + (lane >> 2))) * 1024 + colb;
  const unsigned short* gA1 = gA0 + 16 * 1024;
  const unsigned short* gB0 = Bw + ((long)(tileN * 128 + w * 16 + (lane >> 2))) * 1024 + colb;

#define STAGE(ktile, buf) do {                                             \
    const long ko_ = (long)(ktile) * 32;                                   \
    char* base_ = (char*)sL + (buf) * 24576;                               \
    GLOAD_LDS16(gA0 + ko_, base_ + (w * 2) * 1024 + lane * 16);            \
    GLOAD_LDS16(gA1 + ko_, base_ + (w * 2 + 1) * 1024 + lane * 16);        \
    GLOAD_LDS16(gB0 + ko_, base_ + 16384 + w * 1024 + lane * 16);          \
  } while (0)

  f32x4 acc[4][4] = {};

  STAGE(0, 0);
  STAGE(1, 1);

  int rb = 0, wbuf = 2;
  for (int t = 0; t < 32; ++t) {
    asm volatile("s_waitcnt vmcnt(3)" ::: "memory");
    __builtin_amdgcn_s_barrier();
    int kt = t + 2; if (kt > 31) kt = 31;   // clamped junk stage at tail
    STAGE(kt, wbuf);

    const unsigned short* lb = sL + rb * 12288;
    bf16x8 af[4], bf[4];
#pragma unroll
    for (int i = 0; i < 4; ++i) af[i] = *(const bf16x8*)(lb + offA[i]);
#pragma unroll
    for (int i = 0; i < 4; ++i) bf[i] = *(const bf16x8*)(lb + offB[i]);

    __builtin_amdgcn_s_setprio(1);
#pragma unroll
    for (int mi = 0; mi < 4; ++mi)
#pragma unroll
      for (int ni = 0; ni < 4; ++ni)
        acc[mi][ni] = __builtin_amdgcn_mfma_f32_16x16x32_bf16(af[mi], bf[ni], acc[mi][ni], 0, 0, 0);
    __builtin_amdgcn_s_setprio(0);
    asm volatile("s_waitcnt lgkmcnt(0)" ::: "memory");

    rb = (rb == 2) ? 0 : rb + 1;
    wbuf = (wbuf == 2) ? 0 : wbuf + 1;
  }
  asm volatile("s_waitcnt vmcnt(0)" ::: "memory");
#undef STAGE

  const int m0 = tileM * 256 + wm * 64;
  const int n0 = tileN * 128 + wn * 64;

  if (MODE == 0) {
#pragma unroll
    for (int mi = 0; mi < 4; ++mi) {
      int mrow = m0 + mi * 16 + g * 4;
      int b = mrow >> 9, i = mrow & 511;
#pragma unroll
      for (int ni = 0; ni < 4; ++ni) {
        int n = n0 + ni * 16 + c;
        int mat = n >> 10;
        int cc = n & 1023;
        int h = cc >> 6, d = cc & 63;
        long bh = (long)(b * 16 + h);
        if (mat == 2) {
          unsigned int w0 = f2bf(acc[mi][ni][0]) | ((unsigned)f2bf(acc[mi][ni][1]) << 16);
          unsigned int w1 = f2bf(acc[mi][ni][2]) | ((unsigned)f2bf(acc[mi][ni][3]) << 16);
          *(uint2*)(vt + (bh * 64 + d) * 512 + i) = make_uint2(w0, w1);
        } else {
          float sc = (mat == 0) ? QSCALE : 1.0f;   // prescale Q for exp2 softmax
          unsigned short* dst = (mat == 0 ? qh : kh) + (bh * 512 + i) * 64 + d;
#pragma unroll
          for (int r = 0; r < 4; ++r)
            dst[(long)r * 64] = f2bf(acc[mi][ni][r] * sc);
        }
      }
    }
  } else {
#pragma unroll
    for (int mi = 0; mi < 4; ++mi) {
      int mrow = m0 + mi * 16 + g * 4;
#pragma unroll
      for (int ni = 0; ni < 4; ++ni) {
        int n = n0 + ni * 16 + c;
        float bv = bias[n];
#pragma unroll
        for (int r = 0; r < 4; ++r)
          out[(long)(mrow + r) * 1024 + n] = acc[mi][ni][r] + bv;
      }
    }
  }
}

// ---------------------------------------------------------------------------
// Fused attention v7: R1's structure verbatim (256 blocks x 512 thr, 8 waves
// x 64 q-rows it=4, plain inline loop, NO setprio / NO prefetch macros /
// NO unroll pragma — compiler schedules freely) with exactly one delta vs R1:
// exp2 no-max softmax (Q prescaled by 0.125*log2e in gemm epilogue, lt x8,
// raw v_exp_f32) instead of online-max.
// ---------------------------------------------------------------------------
__global__ __launch_bounds__(512) void k_attn(
    const unsigned short* __restrict__ qh, const unsigned short* __restrict__ kh,
    const unsigned short* __restrict__ vt, const float* __restrict__ rpe,
    const unsigned char* __restrict__ bkt, unsigned short* __restrict__ ao)
{
  __shared__ float lt_lds[512 * 9];
  const int head = blockIdx.x;
  const int b = head >> 4, h = head & 15;
  const int w = threadIdx.x >> 6, lane = threadIdx.x & 63;
  const int g = lane >> 4, c = lane & 15;
  const int qbase = w * 64;
  const unsigned short* Q = qh + (long)head * 512 * 64;
  const unsigned short* K = kh + (long)head * 512 * 64;
  const unsigned short* V = vt + (long)head * 64 * 512;

  // --- load Q fragments (persist; prescaled by QSCALE) ---
  Frag qu[4][2];
#pragma unroll
  for (int it = 0; it < 4; ++it)
#pragma unroll
    for (int kk = 0; kk < 2; ++kk)
      qu[it][kk].v = *(const bf16x8*)(Q + (qbase + it * 16 + c) * 64 + kk * 32 + g * 8);

  // --- lt[i][n] = sum_d q'[i][d]*rpe[d][n]; stored x8 = log2e * lt_orig ---
  float lt[4][7] = {};
#pragma unroll
  for (int kk = 0; kk < 2; ++kk)
#pragma unroll
    for (int tt = 0; tt < 8; ++tt) {
      int d = kk * 32 + g * 8 + tt;
      const float* rr = rpe + d * 7;
      float r0 = rr[0], r1 = rr[1], r2 = rr[2], r3 = rr[3], r4 = rr[4], r5 = rr[5], r6 = rr[6];
#pragma unroll
      for (int it = 0; it < 4; ++it) {
        float qv = bf2f(qu[it][kk].h[tt]);
        lt[it][0] += qv * r0; lt[it][1] += qv * r1; lt[it][2] += qv * r2;
        lt[it][3] += qv * r3; lt[it][4] += qv * r4; lt[it][5] += qv * r5;
        lt[it][6] += qv * r6;
      }
    }
#pragma unroll
  for (int it = 0; it < 4; ++it)
#pragma unroll
    for (int n = 0; n < 7; ++n) {
      float v = lt[it][n];
      v += __shfl_xor(v, 16);
      v += __shfl_xor(v, 32);
      if (g == 0) lt_lds[(qbase + it * 16 + c) * 9 + n] = v * 8.0f;
    }
  // wave-local write->read: no barrier needed

  int rowb36[4];
  const unsigned char* bktp[4];
#pragma unroll
  for (int it = 0; it < 4; ++it) {
    int row = qbase + it * 16 + c;
    rowb36[it] = row * 36;
    bktp[it] = bkt + (long)row * 512 + g * 8;
  }

  f32x4 oacc[4][4] = {};          // [dt][it]
  float lp[4] = {0.f, 0.f, 0.f, 0.f};
  const int jperm = (c >> 2) * 8 + (c & 3);

  for (int jb = 0; jb < 512; jb += 32) {
    // K fragments with row permutation sigma(jt,m) = (m>>2)*8 + jt*4 + (m&3)
    const int jp0 = jb + jperm;
    Frag kf[2][2];
#pragma unroll
    for (int jt = 0; jt < 2; ++jt)
#pragma unroll
      for (int kk = 0; kk < 2; ++kk)
        kf[jt][kk].v = *(const bf16x8*)(K + (jp0 + jt * 4) * 64 + kk * 32 + g * 8);

    uint2 bb[4];
#pragma unroll
    for (int it = 0; it < 4; ++it)
      bb[it] = *(const uint2*)(bktp[it] + jb);

    f32x4 s[2][4];
#pragma unroll
    for (int jt = 0; jt < 2; ++jt)
#pragma unroll
      for (int it = 0; it < 4; ++it) {
        f32x4 z = {0.f, 0.f, 0.f, 0.f};
        z = __builtin_amdgcn_mfma_f32_16x16x32_bf16(kf[jt][0].v, qu[it][0].v, z, 0, 0, 0);
        s[jt][it] = __builtin_amdgcn_mfma_f32_16x16x32_bf16(kf[jt][1].v, qu[it][1].v, z, 0, 0, 0);
      }

    Frag pfr[4];
#pragma unroll
    for (int it = 0; it < 4; ++it) {
      float ps = 0.f;
#pragma unroll
      for (int jt = 0; jt < 2; ++jt) {
        unsigned int bw = jt ? bb[it].y : bb[it].x;
#pragma unroll
        for (int r = 0; r < 4; ++r) {
          int bno = (bw >> (8 * r)) & 255;
          float bias = *(const float*)((const char*)lt_lds + rowb36[it] + (bno << 2));
          float sv = s[jt][it][r] + bias;
          float p;
          asm("v_exp_f32 %0, %1" : "=v"(p) : "v"(sv));
          ps += p;
          pfr[it].hf[jt * 4 + r] = (__bf16)p;
        }
      }
      lp[it] += ps;
    }

    bf16x8 vf[4];
#pragma unroll
    for (int dt = 0; dt < 4; ++dt)
      vf[dt] = *(const bf16x8*)(V + (dt * 16 + c) * 512 + jb + g * 8);

#pragma unroll
    for (int dt = 0; dt < 4; ++dt)
#pragma unroll
      for (int it = 0; it < 4; ++it)
        oacc[dt][it] = __builtin_amdgcn_mfma_f32_16x16x32_bf16(vf[dt], pfr[it].v, oacc[dt][it], 0, 0, 0);
  }

  float li[4];
#pragma unroll
  for (int it = 0; it < 4; ++it) {
    float v = lp[it];
    v += __shfl_xor(v, 16);
    v += __shfl_xor(v, 32);
    li[it] = 1.0f / v;
  }
#pragma unroll
  for (int dt = 0; dt < 4; ++dt)
#pragma unroll
    for (int it = 0; it < 4; ++it) {
      int irow = qbase + it * 16 + c;
      int d0 = dt * 16 + g * 4;
      unsigned int w0 = f2bf(oacc[dt][it][0] * li[it]) | ((unsigned)f2bf(oacc[dt][it][1] * li[it]) << 16);
      unsigned int w1 = f2bf(oacc[dt][it][2] * li[it]) | ((unsigned)f2bf(oacc[dt][it][3] * li[it]) << 16);
      *(uint2*)(ao + ((long)(b * 512 + irow)) * 1024 + h * 64 + d0) = make_uint2(w0, w1);
    }
}

// ---------------------------------------------------------------------------
extern "C" void kernel_launch(void* const* d_in, const int* in_sizes, int n_in,
                              void* d_out, int out_size, void* d_ws, size_t ws_size,
                              hipStream_t stream) {
  const float* x   = (const float*)d_in[0];
  const float* wq  = (const float*)d_in[1];
  const float* wk  = (const float*)d_in[2];
  const float* wv  = (const float*)d_in[3];
  const float* rpe = (const float*)d_in[4];
  const float* pw  = (const float*)d_in[5];
  const float* pb  = (const float*)d_in[6];
  float* out = (float*)d_out;

  char* ws = (char*)d_ws;
  unsigned short* xb  = (unsigned short*)(ws);                 // 8192x1024 bf16 (16 MB)
  unsigned short* wb  = (unsigned short*)(ws + 16777216);      // 4x1024x1024 bf16 (8 MB)
  unsigned short* qhp = (unsigned short*)(ws + 25165824);      // [bh][512][64]
  unsigned short* khp = (unsigned short*)(ws + 41943040);      // [bh][512][64]
  unsigned short* vtp = (unsigned short*)(ws + 58720256);      // [bh][64][512]
  unsigned char*  bkt = (unsigned char*)(ws + 75497472);       // 512x512
  unsigned short* aop = xb;                                    // alias: xb dead after QKV gemm

  k_prep<<<dim3(7168), dim3(256), 0, stream>>>(x, wq, wk, wv, pw, xb, wb, bkt);
  k_gemm<0><<<dim3(768), dim3(512), 0, stream>>>(xb, wb, qhp, khp, vtp, nullptr, nullptr);
  k_attn<<<dim3(256), dim3(512), 0, stream>>>(qhp, khp, vtp, rpe, bkt, aop);
  k_gemm<1><<<dim3(256), dim3(512), 0, stream>>>(aop, wb + 3 * 1048576, nullptr, nullptr, nullptr, out, pb);
}